// Round 1
// baseline (1110.615 us; speedup 1.0000x reference)
//
#include <hip/hip_runtime.h>
#include <cstdint>
#include <cstdio>

#define N_NODES 10000
#define BATCH   32
#define UNITS   64
#define F_DIM   66            // 2 + 64
#define KTOT    (F_DIM*BATCH) // 2112
#define MAXE    128

__device__ __forceinline__ float sigmoidf(float x) {
  return 1.0f / (1.0f + __expf(-x));
}

// ---------------- CSR build ----------------
__global__ __launch_bounds__(256) void hist_k(const int* __restrict__ rows,
                                              int* __restrict__ counts, int E2) {
  int e = blockIdx.x * 256 + threadIdx.x;
  if (e < E2) atomicAdd(&counts[rows[e]], 1);
}

__global__ __launch_bounds__(1024) void scan_k(const int* __restrict__ counts,
                                               int* __restrict__ rowptr,
                                               int* __restrict__ wofs, int n) {
  __shared__ int lds[1024];
  __shared__ int carry;
  if (threadIdx.x == 0) carry = 0;
  __syncthreads();
  for (int base = 0; base < n; base += 1024) {
    int i = base + (int)threadIdx.x;
    int v = (i < n) ? counts[i] : 0;
    lds[threadIdx.x] = v;
    __syncthreads();
    for (int off = 1; off < 1024; off <<= 1) {
      int t = ((int)threadIdx.x >= off) ? lds[threadIdx.x - off] : 0;
      __syncthreads();
      lds[threadIdx.x] += t;
      __syncthreads();
    }
    int incl = lds[threadIdx.x] + carry;
    if (i < n) { rowptr[i] = incl - v; wofs[i] = incl - v; }
    __syncthreads();
    if (threadIdx.x == 1023) carry = incl;
    __syncthreads();
  }
  if (threadIdx.x == 0) rowptr[n] = carry;
}

__global__ __launch_bounds__(256) void scatter_k(const int* __restrict__ rows,
                                                 const int* __restrict__ cols,
                                                 const float* __restrict__ vals,
                                                 int* __restrict__ wofs,
                                                 int* __restrict__ ccol,
                                                 float* __restrict__ cval, int E2) {
  int e = blockIdx.x * 256 + threadIdx.x;
  if (e < E2) {
    int r = rows[e];
    int p = atomicAdd(&wofs[r], 1);
    ccol[p] = cols[e];
    cval[p] = vals[e];
  }
}

// ---------------- feature builds: xcat[n][f*32+b] ----------------
// phase 1: f<2 -> inputs[b][n*2+f], f>=2 -> state[b][n*64+(f-2)]
__global__ __launch_bounds__(256) void build_x1(const float* __restrict__ inputs,
                                                const float* __restrict__ state,
                                                float* __restrict__ xcat) {
  int n = blockIdx.x, t = threadIdx.x;
  __shared__ float T[66 * 33];               // padded transpose tile
  int f = t & 63, bq = t >> 6;               // bq in [0,4)
#pragma unroll
  for (int bb = 0; bb < 8; ++bb) {
    int b = bq + bb * 4;
    T[(f + 2) * 33 + b] = state[(size_t)b * 640000 + (size_t)n * 64 + f];
  }
  if (t < 64) {
    int b0 = t & 31, f0 = t >> 5;
    T[f0 * 33 + b0] = inputs[(size_t)b0 * 20000 + (size_t)n * 2 + f0];
  }
  __syncthreads();
  float* dst = xcat + (size_t)n * KTOT;
#pragma unroll
  for (int i = 0; i < 8; ++i) {
    int k = t + 256 * i;
    dst[k] = T[(k >> 5) * 33 + (k & 31)];
  }
  if (t < 64) {
    int k = 2048 + t;
    dst[k] = T[(k >> 5) * 33 + (k & 31)];
  }
}

// phase 2: f>=2 -> val[n>>1][b][(n&1)*64+(f-2)] * state[b][n*64+(f-2)]
__global__ __launch_bounds__(256) void build_x2(const float* __restrict__ inputs,
                                                const float* __restrict__ state,
                                                const float* __restrict__ val,
                                                float* __restrict__ xcat) {
  int n = blockIdx.x, t = threadIdx.x;
  __shared__ float T[66 * 33];
  int f = t & 63, bq = t >> 6;
  const float* vrow = val + ((size_t)(n >> 1)) * 4096 + (size_t)(n & 1) * 64;
#pragma unroll
  for (int bb = 0; bb < 8; ++bb) {
    int b = bq + bb * 4;
    float s = state[(size_t)b * 640000 + (size_t)n * 64 + f];
    float r = vrow[(size_t)b * 128 + f];
    T[(f + 2) * 33 + b] = r * s;
  }
  if (t < 64) {
    int b0 = t & 31, f0 = t >> 5;
    T[f0 * 33 + b0] = inputs[(size_t)b0 * 20000 + (size_t)n * 2 + f0];
  }
  __syncthreads();
  float* dst = xcat + (size_t)n * KTOT;
#pragma unroll
  for (int i = 0; i < 8; ++i) {
    int k = t + 256 * i;
    dst[k] = T[(k >> 5) * 33 + (k & 31)];
  }
  if (t < 64) {
    int k = 2048 + t;
    dst[k] = T[(k >> 5) * 33 + (k & 31)];
  }
}

// ---------------- phase 1: SpMM + GEMM(66->128) + sigmoid -> val[n][b][128] ----------------
__global__ __launch_bounds__(256) void gcn1(const int* __restrict__ rowptr,
                                            const int* __restrict__ ccol,
                                            const float* __restrict__ cval,
                                            const float* __restrict__ xcat,
                                            const float* __restrict__ w1,
                                            const float* __restrict__ b1,
                                            float* __restrict__ val) {
  int n = blockIdx.x, t = threadIdx.x;
  __shared__ float wL[66 * 128];   // 33792 B
  __shared__ float accL[KTOT];     // 8448 B
  __shared__ int   eC[MAXE];
  __shared__ float eV[MAXE];

  for (int i = t; i < 66 * 128; i += 256) wL[i] = w1[i];

  float racc[9];
#pragma unroll
  for (int i = 0; i < 9; ++i) racc[i] = 0.0f;

  int s = rowptr[n], e = rowptr[n + 1];
  for (int cs = s; cs < e; cs += MAXE) {
    int cnt = min(e - cs, MAXE);
    __syncthreads();
    for (int i = t; i < cnt; i += 256) { eC[i] = ccol[cs + i]; eV[i] = cval[cs + i]; }
    __syncthreads();
    for (int j = 0; j < cnt; ++j) {
      int c = eC[j];
      float v = eV[j];
      const float* src = xcat + (size_t)c * KTOT;
#pragma unroll
      for (int i = 0; i < 8; ++i) racc[i] += v * src[t + 256 * i];
      if (t < 64) racc[8] += v * src[2048 + t];
    }
  }
#pragma unroll
  for (int i = 0; i < 8; ++i) accL[t + 256 * i] = racc[i];
  if (t < 64) accL[2048 + t] = racc[8];
  __syncthreads();

  // GEMM: out[b][j], b = bg*4.., j = jg*4..
  int bg = t >> 5, jg = t & 31;
  float o[4][4];
#pragma unroll
  for (int i = 0; i < 4; ++i)
#pragma unroll
    for (int j = 0; j < 4; ++j) o[i][j] = 0.0f;

  const float4* av = reinterpret_cast<const float4*>(accL);
  const float4* wv = reinterpret_cast<const float4*>(wL);
  for (int f = 0; f < 66; ++f) {
    float4 a = av[f * 8 + bg];
    float4 w = wv[f * 32 + jg];
    o[0][0] += a.x * w.x; o[0][1] += a.x * w.y; o[0][2] += a.x * w.z; o[0][3] += a.x * w.w;
    o[1][0] += a.y * w.x; o[1][1] += a.y * w.y; o[1][2] += a.y * w.z; o[1][3] += a.y * w.w;
    o[2][0] += a.z * w.x; o[2][1] += a.z * w.y; o[2][2] += a.z * w.z; o[2][3] += a.z * w.w;
    o[3][0] += a.w * w.x; o[3][1] += a.w * w.y; o[3][2] += a.w * w.z; o[3][3] += a.w * w.w;
  }

  float4 bb = *reinterpret_cast<const float4*>(b1 + jg * 4);
  float* vb = val + (size_t)n * 4096 + jg * 4;
#pragma unroll
  for (int i = 0; i < 4; ++i) {
    int b = bg * 4 + i;
    float4 r;
    r.x = sigmoidf(o[i][0] + bb.x);
    r.y = sigmoidf(o[i][1] + bb.y);
    r.z = sigmoidf(o[i][2] + bb.z);
    r.w = sigmoidf(o[i][3] + bb.w);
    *reinterpret_cast<float4*>(vb + (size_t)b * 128) = r;
  }
}

// ---------------- phase 2: SpMM + GEMM(66->64) + relu + gate -> out ----------------
__global__ __launch_bounds__(256) void gcn2(const int* __restrict__ rowptr,
                                            const int* __restrict__ ccol,
                                            const float* __restrict__ cval,
                                            const float* __restrict__ xcat,
                                            const float* __restrict__ w2,
                                            const float* __restrict__ b2,
                                            const float* __restrict__ val,
                                            const float* __restrict__ state,
                                            float* __restrict__ out) {
  int n = blockIdx.x, t = threadIdx.x;
  __shared__ float wL[66 * 64];    // 16896 B
  __shared__ float accL[KTOT];
  __shared__ int   eC[MAXE];
  __shared__ float eV[MAXE];

  for (int i = t; i < 66 * 64; i += 256) wL[i] = w2[i];

  float racc[9];
#pragma unroll
  for (int i = 0; i < 9; ++i) racc[i] = 0.0f;

  int s = rowptr[n], e = rowptr[n + 1];
  for (int cs = s; cs < e; cs += MAXE) {
    int cnt = min(e - cs, MAXE);
    __syncthreads();
    for (int i = t; i < cnt; i += 256) { eC[i] = ccol[cs + i]; eV[i] = cval[cs + i]; }
    __syncthreads();
    for (int j = 0; j < cnt; ++j) {
      int c = eC[j];
      float v = eV[j];
      const float* src = xcat + (size_t)c * KTOT;
#pragma unroll
      for (int i = 0; i < 8; ++i) racc[i] += v * src[t + 256 * i];
      if (t < 64) racc[8] += v * src[2048 + t];
    }
  }
#pragma unroll
  for (int i = 0; i < 8; ++i) accL[t + 256 * i] = racc[i];
  if (t < 64) accL[2048 + t] = racc[8];
  __syncthreads();

  // GEMM: out[b][j], b = bg*2.., j = jg*4..  (bg in [0,16), jg in [0,16))
  int bg = t >> 4, jg = t & 15;
  float o[2][4];
#pragma unroll
  for (int i = 0; i < 2; ++i)
#pragma unroll
    for (int j = 0; j < 4; ++j) o[i][j] = 0.0f;

  const float2* av = reinterpret_cast<const float2*>(accL);
  const float4* wv = reinterpret_cast<const float4*>(wL);
  for (int f = 0; f < 66; ++f) {
    float2 a = av[f * 16 + bg];
    float4 w = wv[f * 16 + jg];
    o[0][0] += a.x * w.x; o[0][1] += a.x * w.y; o[0][2] += a.x * w.z; o[0][3] += a.x * w.w;
    o[1][0] += a.y * w.x; o[1][1] += a.y * w.y; o[1][2] += a.y * w.z; o[1][3] += a.y * w.w;
  }

  float4 bb = *reinterpret_cast<const float4*>(b2 + jg * 4);
  int n2 = n >> 1, no = n & 1;
  const float* up = val + ((size_t)(5000 + n2)) * 4096 + (size_t)no * 64 + jg * 4;
#pragma unroll
  for (int i = 0; i < 2; ++i) {
    int b = bg * 2 + i;
    size_t idx = (size_t)b * 640000 + (size_t)n * 64 + jg * 4;
    float4 sv = *reinterpret_cast<const float4*>(state + idx);
    float4 uv = *reinterpret_cast<const float4*>(up + (size_t)b * 128);
    float4 h;
    float c0 = fmaxf(o[i][0] + bb.x, 0.0f);
    float c1 = fmaxf(o[i][1] + bb.y, 0.0f);
    float c2 = fmaxf(o[i][2] + bb.z, 0.0f);
    float c3 = fmaxf(o[i][3] + bb.w, 0.0f);
    h.x = uv.x * sv.x + (1.0f - uv.x) * c0;
    h.y = uv.y * sv.y + (1.0f - uv.y) * c1;
    h.z = uv.z * sv.z + (1.0f - uv.z) * c2;
    h.w = uv.w * sv.w + (1.0f - uv.w) * c3;
    *reinterpret_cast<float4*>(out + idx) = h;
  }
}

// ---------------- host ----------------
static inline size_t alignup(size_t x) { return (x + 255) & ~(size_t)255; }

extern "C" void kernel_launch(void* const* d_in, const int* in_sizes, int n_in,
                              void* d_out, int out_size, void* d_ws, size_t ws_size,
                              hipStream_t stream) {
  const float* inputs = (const float*)d_in[0];
  const float* state  = (const float*)d_in[1];
  const int*   m_rows = (const int*)d_in[2];
  const int*   m_cols = (const int*)d_in[3];
  const float* m_vals = (const float*)d_in[4];
  const float* w1     = (const float*)d_in[5];
  const float* b1     = (const float*)d_in[6];
  const float* w2     = (const float*)d_in[7];
  const float* b2     = (const float*)d_in[8];
  float* out = (float*)d_out;

  const int N  = N_NODES;
  const int E2 = in_sizes[2];

  char* ws = (char*)d_ws;
  size_t off = 0;
  int* counts = (int*)(ws + off); off = alignup(off + (size_t)N * 4);
  int* rowptr = (int*)(ws + off); off = alignup(off + (size_t)(N + 1) * 4);
  int* wofs   = (int*)(ws + off); off = alignup(off + (size_t)N * 4);
  int* ccol   = (int*)(ws + off); off = alignup(off + (size_t)E2 * 4);
  float* cval = (float*)(ws + off); off = alignup(off + (size_t)E2 * 4);
  float* xcat = (float*)(ws + off); off = alignup(off + (size_t)N * KTOT * 4);
  float* val  = (float*)(ws + off); off = alignup(off + (size_t)N * 4096 * 4);
  if (off > ws_size) { return; }  // workspace too small; fail visibly via wrong output

  hipMemsetAsync(counts, 0, (size_t)N * 4, stream);

  int eb = (E2 + 255) / 256;
  hipLaunchKernelGGL(hist_k,    dim3(eb), dim3(256), 0, stream, m_rows, counts, E2);
  hipLaunchKernelGGL(scan_k,    dim3(1),  dim3(1024), 0, stream, counts, rowptr, wofs, N);
  hipLaunchKernelGGL(scatter_k, dim3(eb), dim3(256), 0, stream, m_rows, m_cols, m_vals,
                     wofs, ccol, cval, E2);
  hipLaunchKernelGGL(build_x1,  dim3(N),  dim3(256), 0, stream, inputs, state, xcat);
  hipLaunchKernelGGL(gcn1,      dim3(N),  dim3(256), 0, stream, rowptr, ccol, cval,
                     xcat, w1, b1, val);
  hipLaunchKernelGGL(build_x2,  dim3(N),  dim3(256), 0, stream, inputs, state, val, xcat);
  hipLaunchKernelGGL(gcn2,      dim3(N),  dim3(256), 0, stream, rowptr, ccol, cval,
                     xcat, w2, b2, val, state, out);
}

// Round 2
// 715.470 us; speedup vs baseline: 1.5523x; 1.5523x over previous
//
#include <hip/hip_runtime.h>
#include <hip/hip_fp16.h>
#include <cstdint>
#include <cstdio>

#define N_NODES 10000
#define BATCH   32
#define UNITS   64
#define F_DIM   66            // 2 + 64
#define KTOT    (F_DIM*BATCH) // 2112 elements per node row
#define KH2     (KTOT/2)      // 1056 half2 per node row
#define MAXE    128

__device__ __forceinline__ float sigmoidf(float x) {
  return 1.0f / (1.0f + __expf(-x));
}

// ---------------- CSR build ----------------
__global__ __launch_bounds__(256) void hist_k(const int* __restrict__ rows,
                                              int* __restrict__ counts, int E2) {
  int e = blockIdx.x * 256 + threadIdx.x;
  if (e < E2) atomicAdd(&counts[rows[e]], 1);
}

__global__ __launch_bounds__(1024) void scan_k(const int* __restrict__ counts,
                                               int* __restrict__ rowptr,
                                               int* __restrict__ wofs, int n) {
  __shared__ int lds[1024];
  __shared__ int carry;
  if (threadIdx.x == 0) carry = 0;
  __syncthreads();
  for (int base = 0; base < n; base += 1024) {
    int i = base + (int)threadIdx.x;
    int v = (i < n) ? counts[i] : 0;
    lds[threadIdx.x] = v;
    __syncthreads();
    for (int off = 1; off < 1024; off <<= 1) {
      int t = ((int)threadIdx.x >= off) ? lds[threadIdx.x - off] : 0;
      __syncthreads();
      lds[threadIdx.x] += t;
      __syncthreads();
    }
    int incl = lds[threadIdx.x] + carry;
    if (i < n) { rowptr[i] = incl - v; wofs[i] = incl - v; }
    __syncthreads();
    if (threadIdx.x == 1023) carry = incl;
    __syncthreads();
  }
  if (threadIdx.x == 0) rowptr[n] = carry;
}

__global__ __launch_bounds__(256) void scatter_k(const int* __restrict__ rows,
                                                 const int* __restrict__ cols,
                                                 const float* __restrict__ vals,
                                                 int* __restrict__ wofs,
                                                 int* __restrict__ ccol,
                                                 float* __restrict__ cval, int E2) {
  int e = blockIdx.x * 256 + threadIdx.x;
  if (e < E2) {
    int r = rows[e];
    int p = atomicAdd(&wofs[r], 1);
    ccol[p] = cols[e];
    cval[p] = vals[e];
  }
}

// ---------------- feature builds: xcat[n][f*32+b] as fp16 ----------------
__global__ __launch_bounds__(256) void build_x1(const float* __restrict__ inputs,
                                                const float* __restrict__ state,
                                                __half* __restrict__ xcat) {
  int n = blockIdx.x, t = threadIdx.x;
  __shared__ float T[66 * 33];               // padded transpose tile
  int f = t & 63, bq = t >> 6;               // bq in [0,4)
#pragma unroll
  for (int bb = 0; bb < 8; ++bb) {
    int b = bq + bb * 4;
    T[(f + 2) * 33 + b] = state[(size_t)b * 640000 + (size_t)n * 64 + f];
  }
  if (t < 64) {
    int b0 = t & 31, f0 = t >> 5;
    T[f0 * 33 + b0] = inputs[(size_t)b0 * 20000 + (size_t)n * 2 + f0];
  }
  __syncthreads();
  __half2* dst = reinterpret_cast<__half2*>(xcat + (size_t)n * KTOT);
#pragma unroll
  for (int i = 0; i < 4; ++i) {
    int p = t + 256 * i;                     // half2 index
    int fr = p >> 4, b = (p & 15) << 1;
    dst[p] = __floats2half2_rn(T[fr * 33 + b], T[fr * 33 + b + 1]);
  }
  if (t < 32) {
    int p = 1024 + t;
    int fr = p >> 4, b = (p & 15) << 1;
    dst[p] = __floats2half2_rn(T[fr * 33 + b], T[fr * 33 + b + 1]);
  }
}

__global__ __launch_bounds__(256) void build_x2(const float* __restrict__ inputs,
                                                const float* __restrict__ state,
                                                const float* __restrict__ val,
                                                __half* __restrict__ xcat) {
  int n = blockIdx.x, t = threadIdx.x;
  __shared__ float T[66 * 33];
  int f = t & 63, bq = t >> 6;
  const float* vrow = val + ((size_t)(n >> 1)) * 4096 + (size_t)(n & 1) * 64;
#pragma unroll
  for (int bb = 0; bb < 8; ++bb) {
    int b = bq + bb * 4;
    float s = state[(size_t)b * 640000 + (size_t)n * 64 + f];
    float r = vrow[(size_t)b * 128 + f];
    T[(f + 2) * 33 + b] = r * s;
  }
  if (t < 64) {
    int b0 = t & 31, f0 = t >> 5;
    T[f0 * 33 + b0] = inputs[(size_t)b0 * 20000 + (size_t)n * 2 + f0];
  }
  __syncthreads();
  __half2* dst = reinterpret_cast<__half2*>(xcat + (size_t)n * KTOT);
#pragma unroll
  for (int i = 0; i < 4; ++i) {
    int p = t + 256 * i;
    int fr = p >> 4, b = (p & 15) << 1;
    dst[p] = __floats2half2_rn(T[fr * 33 + b], T[fr * 33 + b + 1]);
  }
  if (t < 32) {
    int p = 1024 + t;
    int fr = p >> 4, b = (p & 15) << 1;
    dst[p] = __floats2half2_rn(T[fr * 33 + b], T[fr * 33 + b + 1]);
  }
}

// ---------------- phase 1: SpMM + GEMM(66->128) + sigmoid -> val[n][b][128] ----------------
__global__ __launch_bounds__(256) void gcn1(const int* __restrict__ rowptr,
                                            const int* __restrict__ ccol,
                                            const float* __restrict__ cval,
                                            const __half* __restrict__ xcat,
                                            const float* __restrict__ w1,
                                            const float* __restrict__ b1,
                                            float* __restrict__ val) {
  int n = blockIdx.x, t = threadIdx.x;
  __shared__ float accL[KTOT];     // 8448 B
  __shared__ int   eC[MAXE];
  __shared__ float eV[MAXE];

  float2 racc[5];
#pragma unroll
  for (int i = 0; i < 5; ++i) { racc[i].x = 0.0f; racc[i].y = 0.0f; }

  int s = rowptr[n], e = rowptr[n + 1];
  for (int cs = s; cs < e; cs += MAXE) {
    int cnt = min(e - cs, MAXE);
    __syncthreads();
    for (int i = t; i < cnt; i += 256) { eC[i] = ccol[cs + i]; eV[i] = cval[cs + i]; }
    __syncthreads();
    for (int j = 0; j < cnt; ++j) {
      int c = eC[j];
      float v = eV[j];
      const __half2* src = reinterpret_cast<const __half2*>(xcat + (size_t)c * KTOT);
#pragma unroll
      for (int i = 0; i < 4; ++i) {
        float2 x = __half22float2(src[t + 256 * i]);
        racc[i].x += v * x.x; racc[i].y += v * x.y;
      }
      if (t < 32) {
        float2 x = __half22float2(src[1024 + t]);
        racc[4].x += v * x.x; racc[4].y += v * x.y;
      }
    }
  }
  float2* accV = reinterpret_cast<float2*>(accL);
#pragma unroll
  for (int i = 0; i < 4; ++i) accV[t + 256 * i] = racc[i];
  if (t < 32) accV[1024 + t] = racc[4];
  __syncthreads();

  // GEMM: out[b][j], b = bg*4.., j = jg*4..
  int bg = t >> 5, jg = t & 31;
  float o[4][4];
#pragma unroll
  for (int i = 0; i < 4; ++i)
#pragma unroll
    for (int j = 0; j < 4; ++j) o[i][j] = 0.0f;

  const float4* av = reinterpret_cast<const float4*>(accL);
  const float4* wv = reinterpret_cast<const float4*>(w1);
  for (int f = 0; f < 66; ++f) {
    float4 a = av[f * 8 + bg];
    float4 w = wv[f * 32 + jg];
    o[0][0] += a.x * w.x; o[0][1] += a.x * w.y; o[0][2] += a.x * w.z; o[0][3] += a.x * w.w;
    o[1][0] += a.y * w.x; o[1][1] += a.y * w.y; o[1][2] += a.y * w.z; o[1][3] += a.y * w.w;
    o[2][0] += a.z * w.x; o[2][1] += a.z * w.y; o[2][2] += a.z * w.z; o[2][3] += a.z * w.w;
    o[3][0] += a.w * w.x; o[3][1] += a.w * w.y; o[3][2] += a.w * w.z; o[3][3] += a.w * w.w;
  }

  float4 bb = *reinterpret_cast<const float4*>(b1 + jg * 4);
  float* vb = val + (size_t)n * 4096 + jg * 4;
#pragma unroll
  for (int i = 0; i < 4; ++i) {
    int b = bg * 4 + i;
    float4 r;
    r.x = sigmoidf(o[i][0] + bb.x);
    r.y = sigmoidf(o[i][1] + bb.y);
    r.z = sigmoidf(o[i][2] + bb.z);
    r.w = sigmoidf(o[i][3] + bb.w);
    *reinterpret_cast<float4*>(vb + (size_t)b * 128) = r;
  }
}

// ---------------- phase 2: SpMM + GEMM(66->64) + relu + gate -> out ----------------
__global__ __launch_bounds__(256) void gcn2(const int* __restrict__ rowptr,
                                            const int* __restrict__ ccol,
                                            const float* __restrict__ cval,
                                            const __half* __restrict__ xcat,
                                            const float* __restrict__ w2,
                                            const float* __restrict__ b2,
                                            const float* __restrict__ val,
                                            const float* __restrict__ state,
                                            float* __restrict__ out) {
  int n = blockIdx.x, t = threadIdx.x;
  __shared__ float accL[KTOT];
  __shared__ int   eC[MAXE];
  __shared__ float eV[MAXE];

  float2 racc[5];
#pragma unroll
  for (int i = 0; i < 5; ++i) { racc[i].x = 0.0f; racc[i].y = 0.0f; }

  int s = rowptr[n], e = rowptr[n + 1];
  for (int cs = s; cs < e; cs += MAXE) {
    int cnt = min(e - cs, MAXE);
    __syncthreads();
    for (int i = t; i < cnt; i += 256) { eC[i] = ccol[cs + i]; eV[i] = cval[cs + i]; }
    __syncthreads();
    for (int j = 0; j < cnt; ++j) {
      int c = eC[j];
      float v = eV[j];
      const __half2* src = reinterpret_cast<const __half2*>(xcat + (size_t)c * KTOT);
#pragma unroll
      for (int i = 0; i < 4; ++i) {
        float2 x = __half22float2(src[t + 256 * i]);
        racc[i].x += v * x.x; racc[i].y += v * x.y;
      }
      if (t < 32) {
        float2 x = __half22float2(src[1024 + t]);
        racc[4].x += v * x.x; racc[4].y += v * x.y;
      }
    }
  }
  float2* accV = reinterpret_cast<float2*>(accL);
#pragma unroll
  for (int i = 0; i < 4; ++i) accV[t + 256 * i] = racc[i];
  if (t < 32) accV[1024 + t] = racc[4];
  __syncthreads();

  // GEMM: out[b][j], b = bg*2.., j = jg*4..  (bg in [0,16), jg in [0,16))
  int bg = t >> 4, jg = t & 15;
  float o[2][4];
#pragma unroll
  for (int i = 0; i < 2; ++i)
#pragma unroll
    for (int j = 0; j < 4; ++j) o[i][j] = 0.0f;

  const float2* av = reinterpret_cast<const float2*>(accL);
  const float4* wv = reinterpret_cast<const float4*>(w2);
  for (int f = 0; f < 66; ++f) {
    float2 a = av[f * 16 + bg];
    float4 w = wv[f * 16 + jg];
    o[0][0] += a.x * w.x; o[0][1] += a.x * w.y; o[0][2] += a.x * w.z; o[0][3] += a.x * w.w;
    o[1][0] += a.y * w.x; o[1][1] += a.y * w.y; o[1][2] += a.y * w.z; o[1][3] += a.y * w.w;
  }

  float4 bb = *reinterpret_cast<const float4*>(b2 + jg * 4);
  int n2 = n >> 1, no = n & 1;
  const float* up = val + ((size_t)(5000 + n2)) * 4096 + (size_t)no * 64 + jg * 4;
#pragma unroll
  for (int i = 0; i < 2; ++i) {
    int b = bg * 2 + i;
    size_t idx = (size_t)b * 640000 + (size_t)n * 64 + jg * 4;
    float4 sv = *reinterpret_cast<const float4*>(state + idx);
    float4 uv = *reinterpret_cast<const float4*>(up + (size_t)b * 128);
    float4 h;
    float c0 = fmaxf(o[i][0] + bb.x, 0.0f);
    float c1 = fmaxf(o[i][1] + bb.y, 0.0f);
    float c2 = fmaxf(o[i][2] + bb.z, 0.0f);
    float c3 = fmaxf(o[i][3] + bb.w, 0.0f);
    h.x = uv.x * sv.x + (1.0f - uv.x) * c0;
    h.y = uv.y * sv.y + (1.0f - uv.y) * c1;
    h.z = uv.z * sv.z + (1.0f - uv.z) * c2;
    h.w = uv.w * sv.w + (1.0f - uv.w) * c3;
    *reinterpret_cast<float4*>(out + idx) = h;
  }
}

// ---------------- host ----------------
static inline size_t alignup(size_t x) { return (x + 255) & ~(size_t)255; }

extern "C" void kernel_launch(void* const* d_in, const int* in_sizes, int n_in,
                              void* d_out, int out_size, void* d_ws, size_t ws_size,
                              hipStream_t stream) {
  const float* inputs = (const float*)d_in[0];
  const float* state  = (const float*)d_in[1];
  const int*   m_rows = (const int*)d_in[2];
  const int*   m_cols = (const int*)d_in[3];
  const float* m_vals = (const float*)d_in[4];
  const float* w1     = (const float*)d_in[5];
  const float* b1     = (const float*)d_in[6];
  const float* w2     = (const float*)d_in[7];
  const float* b2     = (const float*)d_in[8];
  float* out = (float*)d_out;

  const int N  = N_NODES;
  const int E2 = in_sizes[2];

  char* ws = (char*)d_ws;
  size_t off = 0;
  int* counts = (int*)(ws + off); off = alignup(off + (size_t)N * 4);
  int* rowptr = (int*)(ws + off); off = alignup(off + (size_t)(N + 1) * 4);
  int* wofs   = (int*)(ws + off); off = alignup(off + (size_t)N * 4);
  int* ccol   = (int*)(ws + off); off = alignup(off + (size_t)E2 * 4);
  float* cval = (float*)(ws + off); off = alignup(off + (size_t)E2 * 4);
  __half* xcat = (__half*)(ws + off); off = alignup(off + (size_t)N * KTOT * 2);
  float* val  = (float*)(ws + off); off = alignup(off + (size_t)N * 4096 * 4);
  if (off > ws_size) { return; }

  hipMemsetAsync(counts, 0, (size_t)N * 4, stream);

  int eb = (E2 + 255) / 256;
  hipLaunchKernelGGL(hist_k,    dim3(eb), dim3(256), 0, stream, m_rows, counts, E2);
  hipLaunchKernelGGL(scan_k,    dim3(1),  dim3(1024), 0, stream, counts, rowptr, wofs, N);
  hipLaunchKernelGGL(scatter_k, dim3(eb), dim3(256), 0, stream, m_rows, m_cols, m_vals,
                     wofs, ccol, cval, E2);
  hipLaunchKernelGGL(build_x1,  dim3(N),  dim3(256), 0, stream, inputs, state, xcat);
  hipLaunchKernelGGL(gcn1,      dim3(N),  dim3(256), 0, stream, rowptr, ccol, cval,
                     xcat, w1, b1, val);
  hipLaunchKernelGGL(build_x2,  dim3(N),  dim3(256), 0, stream, inputs, state, val, xcat);
  hipLaunchKernelGGL(gcn2,      dim3(N),  dim3(256), 0, stream, rowptr, ccol, cval,
                     xcat, w2, b2, val, state, out);
}

// Round 3
// 688.440 us; speedup vs baseline: 1.6132x; 1.0393x over previous
//
#include <hip/hip_runtime.h>
#include <hip/hip_fp16.h>
#include <cstdint>
#include <cstdio>

#define N_NODES 10000
#define BATCH   32
#define UNITS   64
#define F_DIM   66            // 2 + 64
#define KTOT    (F_DIM*BATCH) // 2112 halves per node row = 4224 B = 264 x 16B chunks
#define MAXE    128

__device__ __forceinline__ float sigmoidf(float x) {
  return 1.0f / (1.0f + __expf(-x));
}

// ---------------- CSR build ----------------
__global__ __launch_bounds__(256) void hist_k(const int* __restrict__ rows,
                                              int* __restrict__ counts, int E2) {
  int e = blockIdx.x * 256 + threadIdx.x;
  if (e < E2) atomicAdd(&counts[rows[e]], 1);
}

__global__ __launch_bounds__(1024) void scan_k(const int* __restrict__ counts,
                                               int* __restrict__ rowptr,
                                               int* __restrict__ wofs, int n) {
  __shared__ int lds[1024];
  __shared__ int carry;
  if (threadIdx.x == 0) carry = 0;
  __syncthreads();
  for (int base = 0; base < n; base += 1024) {
    int i = base + (int)threadIdx.x;
    int v = (i < n) ? counts[i] : 0;
    lds[threadIdx.x] = v;
    __syncthreads();
    for (int off = 1; off < 1024; off <<= 1) {
      int t = ((int)threadIdx.x >= off) ? lds[threadIdx.x - off] : 0;
      __syncthreads();
      lds[threadIdx.x] += t;
      __syncthreads();
    }
    int incl = lds[threadIdx.x] + carry;
    if (i < n) { rowptr[i] = incl - v; wofs[i] = incl - v; }
    __syncthreads();
    if (threadIdx.x == 1023) carry = incl;
    __syncthreads();
  }
  if (threadIdx.x == 0) rowptr[n] = carry;
}

__global__ __launch_bounds__(256) void scatter_k(const int* __restrict__ rows,
                                                 const int* __restrict__ cols,
                                                 const float* __restrict__ vals,
                                                 int* __restrict__ wofs,
                                                 int* __restrict__ ccol,
                                                 float* __restrict__ cval, int E2) {
  int e = blockIdx.x * 256 + threadIdx.x;
  if (e < E2) {
    int r = rows[e];
    int p = atomicAdd(&wofs[r], 1);
    ccol[p] = cols[e];
    cval[p] = vals[e];
  }
}

// ---------------- feature builds: xcat[n][f*32+b] as fp16 ----------------
__global__ __launch_bounds__(256) void build_x1(const float* __restrict__ inputs,
                                                const float* __restrict__ state,
                                                __half* __restrict__ xcat) {
  int n = blockIdx.x, t = threadIdx.x;
  __shared__ float T[66 * 33];               // padded transpose tile
  int f = t & 63, bq = t >> 6;               // bq in [0,4)
#pragma unroll
  for (int bb = 0; bb < 8; ++bb) {
    int b = bq + bb * 4;
    T[(f + 2) * 33 + b] = state[(size_t)b * 640000 + (size_t)n * 64 + f];
  }
  if (t < 64) {
    int b0 = t & 31, f0 = t >> 5;
    T[f0 * 33 + b0] = inputs[(size_t)b0 * 20000 + (size_t)n * 2 + f0];
  }
  __syncthreads();
  __half2* dst = reinterpret_cast<__half2*>(xcat + (size_t)n * KTOT);
#pragma unroll
  for (int i = 0; i < 4; ++i) {
    int p = t + 256 * i;                     // half2 index
    int fr = p >> 4, b = (p & 15) << 1;
    dst[p] = __floats2half2_rn(T[fr * 33 + b], T[fr * 33 + b + 1]);
  }
  if (t < 32) {
    int p = 1024 + t;
    int fr = p >> 4, b = (p & 15) << 1;
    dst[p] = __floats2half2_rn(T[fr * 33 + b], T[fr * 33 + b + 1]);
  }
}

__global__ __launch_bounds__(256) void build_x2(const float* __restrict__ inputs,
                                                const float* __restrict__ state,
                                                const __half* __restrict__ val,
                                                __half* __restrict__ xcat) {
  int n = blockIdx.x, t = threadIdx.x;
  __shared__ float T[66 * 33];
  int f = t & 63, bq = t >> 6;
  const __half* vrow = val + ((size_t)(n >> 1)) * 4096 + (size_t)(n & 1) * 64;
#pragma unroll
  for (int bb = 0; bb < 8; ++bb) {
    int b = bq + bb * 4;
    float s = state[(size_t)b * 640000 + (size_t)n * 64 + f];
    float r = __half2float(vrow[(size_t)b * 128 + f]);
    T[(f + 2) * 33 + b] = r * s;
  }
  if (t < 64) {
    int b0 = t & 31, f0 = t >> 5;
    T[f0 * 33 + b0] = inputs[(size_t)b0 * 20000 + (size_t)n * 2 + f0];
  }
  __syncthreads();
  __half2* dst = reinterpret_cast<__half2*>(xcat + (size_t)n * KTOT);
#pragma unroll
  for (int i = 0; i < 4; ++i) {
    int p = t + 256 * i;
    int fr = p >> 4, b = (p & 15) << 1;
    dst[p] = __floats2half2_rn(T[fr * 33 + b], T[fr * 33 + b + 1]);
  }
  if (t < 32) {
    int p = 1024 + t;
    int fr = p >> 4, b = (p & 15) << 1;
    dst[p] = __floats2half2_rn(T[fr * 33 + b], T[fr * 33 + b + 1]);
  }
}

// Consume one 16B chunk (8 halves) into 8 fp32 accumulators.
__device__ __forceinline__ void consume8(const uint4& raw, float v, float* acc) {
  const __half2* h = reinterpret_cast<const __half2*>(&raw);
#pragma unroll
  for (int i = 0; i < 4; ++i) {
    float2 x = __half22float2(h[i]);
    acc[2 * i]     += v * x.x;
    acc[2 * i + 1] += v * x.y;
  }
}

// ---------------- phase 1: SpMM + GEMM(66->128) + sigmoid -> val[n][b][128] fp16 ----------------
__global__ __launch_bounds__(256) void gcn1(const int* __restrict__ rowptr,
                                            const int* __restrict__ ccol,
                                            const float* __restrict__ cval,
                                            const __half* __restrict__ xcat,
                                            const float* __restrict__ w1,
                                            const float* __restrict__ b1,
                                            __half* __restrict__ val) {
  int n = blockIdx.x, t = threadIdx.x;
  __shared__ float accL[KTOT];     // 8448 B
  __shared__ int   eC[MAXE];
  __shared__ float eV[MAXE];

  float racc[8], rtail[8];
#pragma unroll
  for (int i = 0; i < 8; ++i) { racc[i] = 0.0f; rtail[i] = 0.0f; }
  bool tail = (t < 8);

  int s = rowptr[n], e = rowptr[n + 1];
  for (int cs = s; cs < e; cs += MAXE) {
    int cnt = min(e - cs, MAXE);
    __syncthreads();
    for (int i = t; i < cnt; i += 256) { eC[i] = ccol[cs + i]; eV[i] = cval[cs + i]; }
    __syncthreads();
    // 2-deep software pipeline over edges; 16B loads per thread
    uint4 A, At = make_uint4(0,0,0,0);
    float vA;
    {
      int c = eC[0]; vA = eV[0];
      const uint4* src = reinterpret_cast<const uint4*>(xcat + (size_t)c * KTOT);
      A = src[t];
      if (tail) At = src[256 + t];
    }
    int j = 0;
    for (; j + 1 < cnt; ++j) {
      uint4 B, Bt = make_uint4(0,0,0,0);
      float vB;
      {
        int c = eC[j + 1]; vB = eV[j + 1];
        const uint4* src = reinterpret_cast<const uint4*>(xcat + (size_t)c * KTOT);
        B = src[t];
        if (tail) Bt = src[256 + t];
      }
      consume8(A, vA, racc);
      if (tail) consume8(At, vA, rtail);
      A = B; At = Bt; vA = vB;
    }
    consume8(A, vA, racc);
    if (tail) consume8(At, vA, rtail);
  }
  float4* a4 = reinterpret_cast<float4*>(accL);
  a4[2 * t]     = make_float4(racc[0], racc[1], racc[2], racc[3]);
  a4[2 * t + 1] = make_float4(racc[4], racc[5], racc[6], racc[7]);
  if (tail) {
    a4[512 + 2 * t]     = make_float4(rtail[0], rtail[1], rtail[2], rtail[3]);
    a4[512 + 2 * t + 1] = make_float4(rtail[4], rtail[5], rtail[6], rtail[7]);
  }
  __syncthreads();

  // GEMM: out[b][j], b = bg*4.., j = jg*4..
  int bg = t >> 5, jg = t & 31;
  float o[4][4];
#pragma unroll
  for (int i = 0; i < 4; ++i)
#pragma unroll
    for (int j2 = 0; j2 < 4; ++j2) o[i][j2] = 0.0f;

  const float4* av = reinterpret_cast<const float4*>(accL);
  const float4* wv = reinterpret_cast<const float4*>(w1);
  for (int f = 0; f < 66; ++f) {
    float4 a = av[f * 8 + bg];
    float4 w = wv[f * 32 + jg];
    o[0][0] += a.x * w.x; o[0][1] += a.x * w.y; o[0][2] += a.x * w.z; o[0][3] += a.x * w.w;
    o[1][0] += a.y * w.x; o[1][1] += a.y * w.y; o[1][2] += a.y * w.z; o[1][3] += a.y * w.w;
    o[2][0] += a.z * w.x; o[2][1] += a.z * w.y; o[2][2] += a.z * w.z; o[2][3] += a.z * w.w;
    o[3][0] += a.w * w.x; o[3][1] += a.w * w.y; o[3][2] += a.w * w.z; o[3][3] += a.w * w.w;
  }

  float4 bb = *reinterpret_cast<const float4*>(b1 + jg * 4);
  __half* vb = val + (size_t)n * 4096 + jg * 4;
#pragma unroll
  for (int i = 0; i < 4; ++i) {
    int b = bg * 4 + i;
    union { __half2 h[2]; uint2 u; } pk;
    pk.h[0] = __floats2half2_rn(sigmoidf(o[i][0] + bb.x), sigmoidf(o[i][1] + bb.y));
    pk.h[1] = __floats2half2_rn(sigmoidf(o[i][2] + bb.z), sigmoidf(o[i][3] + bb.w));
    *reinterpret_cast<uint2*>(vb + (size_t)b * 128) = pk.u;
  }
}

// ---------------- phase 2: SpMM + GEMM(66->64) + relu + gate -> out ----------------
__global__ __launch_bounds__(256) void gcn2(const int* __restrict__ rowptr,
                                            const int* __restrict__ ccol,
                                            const float* __restrict__ cval,
                                            const __half* __restrict__ xcat,
                                            const float* __restrict__ w2,
                                            const float* __restrict__ b2,
                                            const __half* __restrict__ val,
                                            const float* __restrict__ state,
                                            float* __restrict__ out) {
  int n = blockIdx.x, t = threadIdx.x;
  __shared__ float accL[KTOT];
  __shared__ int   eC[MAXE];
  __shared__ float eV[MAXE];

  float racc[8], rtail[8];
#pragma unroll
  for (int i = 0; i < 8; ++i) { racc[i] = 0.0f; rtail[i] = 0.0f; }
  bool tail = (t < 8);

  int s = rowptr[n], e = rowptr[n + 1];
  for (int cs = s; cs < e; cs += MAXE) {
    int cnt = min(e - cs, MAXE);
    __syncthreads();
    for (int i = t; i < cnt; i += 256) { eC[i] = ccol[cs + i]; eV[i] = cval[cs + i]; }
    __syncthreads();
    uint4 A, At = make_uint4(0,0,0,0);
    float vA;
    {
      int c = eC[0]; vA = eV[0];
      const uint4* src = reinterpret_cast<const uint4*>(xcat + (size_t)c * KTOT);
      A = src[t];
      if (tail) At = src[256 + t];
    }
    int j = 0;
    for (; j + 1 < cnt; ++j) {
      uint4 B, Bt = make_uint4(0,0,0,0);
      float vB;
      {
        int c = eC[j + 1]; vB = eV[j + 1];
        const uint4* src = reinterpret_cast<const uint4*>(xcat + (size_t)c * KTOT);
        B = src[t];
        if (tail) Bt = src[256 + t];
      }
      consume8(A, vA, racc);
      if (tail) consume8(At, vA, rtail);
      A = B; At = Bt; vA = vB;
    }
    consume8(A, vA, racc);
    if (tail) consume8(At, vA, rtail);
  }
  float4* a4 = reinterpret_cast<float4*>(accL);
  a4[2 * t]     = make_float4(racc[0], racc[1], racc[2], racc[3]);
  a4[2 * t + 1] = make_float4(racc[4], racc[5], racc[6], racc[7]);
  if (tail) {
    a4[512 + 2 * t]     = make_float4(rtail[0], rtail[1], rtail[2], rtail[3]);
    a4[512 + 2 * t + 1] = make_float4(rtail[4], rtail[5], rtail[6], rtail[7]);
  }
  __syncthreads();

  // GEMM: out[b][j], b = bg*2.., j = jg*4..  (bg in [0,16), jg in [0,16))
  int bg = t >> 4, jg = t & 15;
  float o[2][4];
#pragma unroll
  for (int i = 0; i < 2; ++i)
#pragma unroll
    for (int j2 = 0; j2 < 4; ++j2) o[i][j2] = 0.0f;

  const float2* av = reinterpret_cast<const float2*>(accL);
  const float4* wv = reinterpret_cast<const float4*>(w2);
  for (int f = 0; f < 66; ++f) {
    float2 a = av[f * 16 + bg];
    float4 w = wv[f * 16 + jg];
    o[0][0] += a.x * w.x; o[0][1] += a.x * w.y; o[0][2] += a.x * w.z; o[0][3] += a.x * w.w;
    o[1][0] += a.y * w.x; o[1][1] += a.y * w.y; o[1][2] += a.y * w.z; o[1][3] += a.y * w.w;
  }

  float4 bb = *reinterpret_cast<const float4*>(b2 + jg * 4);
  int n2 = n >> 1, no = n & 1;
  const __half* up = val + ((size_t)(5000 + n2)) * 4096 + (size_t)no * 64 + jg * 4;
#pragma unroll
  for (int i = 0; i < 2; ++i) {
    int b = bg * 2 + i;
    size_t idx = (size_t)b * 640000 + (size_t)n * 64 + jg * 4;
    float4 sv = *reinterpret_cast<const float4*>(state + idx);
    union { uint2 u; __half2 h[2]; } pk;
    pk.u = *reinterpret_cast<const uint2*>(up + (size_t)b * 128);
    float2 u01 = __half22float2(pk.h[0]);
    float2 u23 = __half22float2(pk.h[1]);
    float4 h;
    float c0 = fmaxf(o[i][0] + bb.x, 0.0f);
    float c1 = fmaxf(o[i][1] + bb.y, 0.0f);
    float c2 = fmaxf(o[i][2] + bb.z, 0.0f);
    float c3 = fmaxf(o[i][3] + bb.w, 0.0f);
    h.x = u01.x * sv.x + (1.0f - u01.x) * c0;
    h.y = u01.y * sv.y + (1.0f - u01.y) * c1;
    h.z = u23.x * sv.z + (1.0f - u23.x) * c2;
    h.w = u23.y * sv.w + (1.0f - u23.y) * c3;
    *reinterpret_cast<float4*>(out + idx) = h;
  }
}

// ---------------- host ----------------
static inline size_t alignup(size_t x) { return (x + 255) & ~(size_t)255; }

extern "C" void kernel_launch(void* const* d_in, const int* in_sizes, int n_in,
                              void* d_out, int out_size, void* d_ws, size_t ws_size,
                              hipStream_t stream) {
  const float* inputs = (const float*)d_in[0];
  const float* state  = (const float*)d_in[1];
  const int*   m_rows = (const int*)d_in[2];
  const int*   m_cols = (const int*)d_in[3];
  const float* m_vals = (const float*)d_in[4];
  const float* w1     = (const float*)d_in[5];
  const float* b1     = (const float*)d_in[6];
  const float* w2     = (const float*)d_in[7];
  const float* b2     = (const float*)d_in[8];
  float* out = (float*)d_out;

  const int N  = N_NODES;
  const int E2 = in_sizes[2];

  char* ws = (char*)d_ws;
  size_t off = 0;
  int* counts = (int*)(ws + off); off = alignup(off + (size_t)N * 4);
  int* rowptr = (int*)(ws + off); off = alignup(off + (size_t)(N + 1) * 4);
  int* wofs   = (int*)(ws + off); off = alignup(off + (size_t)N * 4);
  int* ccol   = (int*)(ws + off); off = alignup(off + (size_t)E2 * 4);
  float* cval = (float*)(ws + off); off = alignup(off + (size_t)E2 * 4);
  __half* xcat = (__half*)(ws + off); off = alignup(off + (size_t)N * KTOT * 2);
  __half* val  = (__half*)(ws + off); off = alignup(off + (size_t)N * 4096 * 2);
  if (off > ws_size) { return; }

  hipMemsetAsync(counts, 0, (size_t)N * 4, stream);

  int eb = (E2 + 255) / 256;
  hipLaunchKernelGGL(hist_k,    dim3(eb), dim3(256), 0, stream, m_rows, counts, E2);
  hipLaunchKernelGGL(scan_k,    dim3(1),  dim3(1024), 0, stream, counts, rowptr, wofs, N);
  hipLaunchKernelGGL(scatter_k, dim3(eb), dim3(256), 0, stream, m_rows, m_cols, m_vals,
                     wofs, ccol, cval, E2);
  hipLaunchKernelGGL(build_x1,  dim3(N),  dim3(256), 0, stream, inputs, state, xcat);
  hipLaunchKernelGGL(gcn1,      dim3(N),  dim3(256), 0, stream, rowptr, ccol, cval,
                     xcat, w1, b1, val);
  hipLaunchKernelGGL(build_x2,  dim3(N),  dim3(256), 0, stream, inputs, state, val, xcat);
  hipLaunchKernelGGL(gcn2,      dim3(N),  dim3(256), 0, stream, rowptr, ccol, cval,
                     xcat, w2, b2, val, state, out);
}

// Round 4
// 658.196 us; speedup vs baseline: 1.6874x; 1.0460x over previous
//
#include <hip/hip_runtime.h>
#include <hip/hip_fp16.h>
#include <cstdint>
#include <cstdio>

#define N_NODES 10000
#define BATCH   32
#define UNITS   64
#define F_DIM   66            // 2 + 64
#define KTOT    (F_DIM*BATCH) // 2112 halves per node row = 4224 B = 264 x 16B chunks
#define MAXE    128

__device__ __forceinline__ float sigmoidf(float x) {
  return 1.0f / (1.0f + __expf(-x));
}

// ---------------- CSR build ----------------
__global__ __launch_bounds__(256) void hist_k(const int* __restrict__ rows,
                                              int* __restrict__ counts, int E2) {
  int e = blockIdx.x * 256 + threadIdx.x;
  if (e < E2) atomicAdd(&counts[rows[e]], 1);
}

__global__ __launch_bounds__(1024) void scan_k(const int* __restrict__ counts,
                                               int* __restrict__ rowptr,
                                               int* __restrict__ wofs, int n) {
  __shared__ int lds[1024];
  __shared__ int carry;
  if (threadIdx.x == 0) carry = 0;
  __syncthreads();
  for (int base = 0; base < n; base += 1024) {
    int i = base + (int)threadIdx.x;
    int v = (i < n) ? counts[i] : 0;
    lds[threadIdx.x] = v;
    __syncthreads();
    for (int off = 1; off < 1024; off <<= 1) {
      int t = ((int)threadIdx.x >= off) ? lds[threadIdx.x - off] : 0;
      __syncthreads();
      lds[threadIdx.x] += t;
      __syncthreads();
    }
    int incl = lds[threadIdx.x] + carry;
    if (i < n) { rowptr[i] = incl - v; wofs[i] = incl - v; }
    __syncthreads();
    if (threadIdx.x == 1023) carry = incl;
    __syncthreads();
  }
  if (threadIdx.x == 0) rowptr[n] = carry;
}

__global__ __launch_bounds__(256) void scatter_k(const int* __restrict__ rows,
                                                 const int* __restrict__ cols,
                                                 const float* __restrict__ vals,
                                                 int* __restrict__ wofs,
                                                 int* __restrict__ ccol,
                                                 float* __restrict__ cval, int E2) {
  int e = blockIdx.x * 256 + threadIdx.x;
  if (e < E2) {
    int r = rows[e];
    int p = atomicAdd(&wofs[r], 1);
    ccol[p] = cols[e];
    cval[p] = vals[e];
  }
}

// ---------------- feature builds: xcat[n][f*32+b] as fp16 ----------------
__global__ __launch_bounds__(256) void build_x1(const float* __restrict__ inputs,
                                                const float* __restrict__ state,
                                                __half* __restrict__ xcat) {
  int n = blockIdx.x, t = threadIdx.x;
  __shared__ float T[66 * 33];               // padded transpose tile
  int f = t & 63, bq = t >> 6;               // bq in [0,4)
#pragma unroll
  for (int bb = 0; bb < 8; ++bb) {
    int b = bq + bb * 4;
    T[(f + 2) * 33 + b] = state[(size_t)b * 640000 + (size_t)n * 64 + f];
  }
  if (t < 64) {
    int b0 = t & 31, f0 = t >> 5;
    T[f0 * 33 + b0] = inputs[(size_t)b0 * 20000 + (size_t)n * 2 + f0];
  }
  __syncthreads();
  __half2* dst = reinterpret_cast<__half2*>(xcat + (size_t)n * KTOT);
#pragma unroll
  for (int i = 0; i < 4; ++i) {
    int p = t + 256 * i;                     // half2 index
    int fr = p >> 4, b = (p & 15) << 1;
    dst[p] = __floats2half2_rn(T[fr * 33 + b], T[fr * 33 + b + 1]);
  }
  if (t < 32) {
    int p = 1024 + t;
    int fr = p >> 4, b = (p & 15) << 1;
    dst[p] = __floats2half2_rn(T[fr * 33 + b], T[fr * 33 + b + 1]);
  }
}

__global__ __launch_bounds__(256) void build_x2(const float* __restrict__ inputs,
                                                const float* __restrict__ state,
                                                const __half* __restrict__ val,
                                                __half* __restrict__ xcat) {
  int n = blockIdx.x, t = threadIdx.x;
  __shared__ float T[66 * 33];
  int f = t & 63, bq = t >> 6;
  const __half* vrow = val + ((size_t)(n >> 1)) * 4096 + (size_t)(n & 1) * 64;
#pragma unroll
  for (int bb = 0; bb < 8; ++bb) {
    int b = bq + bb * 4;
    float s = state[(size_t)b * 640000 + (size_t)n * 64 + f];
    float r = __half2float(vrow[(size_t)b * 128 + f]);
    T[(f + 2) * 33 + b] = r * s;
  }
  if (t < 64) {
    int b0 = t & 31, f0 = t >> 5;
    T[f0 * 33 + b0] = inputs[(size_t)b0 * 20000 + (size_t)n * 2 + f0];
  }
  __syncthreads();
  __half2* dst = reinterpret_cast<__half2*>(xcat + (size_t)n * KTOT);
#pragma unroll
  for (int i = 0; i < 4; ++i) {
    int p = t + 256 * i;
    int fr = p >> 4, b = (p & 15) << 1;
    dst[p] = __floats2half2_rn(T[fr * 33 + b], T[fr * 33 + b + 1]);
  }
  if (t < 32) {
    int p = 1024 + t;
    int fr = p >> 4, b = (p & 15) << 1;
    dst[p] = __floats2half2_rn(T[fr * 33 + b], T[fr * 33 + b + 1]);
  }
}

// ---------------- yin = M @ X_in  (input-feature part, shared by both passes) ----------------
// yin[n][k], k = f*32+b for f<2 (64 floats/node). 8 threads per node, 32 nodes/block.
__global__ __launch_bounds__(256) void yin_k(const int* __restrict__ rowptr,
                                             const int* __restrict__ ccol,
                                             const float* __restrict__ cval,
                                             const __half* __restrict__ xcat,
                                             float* __restrict__ yin) {
  int n = blockIdx.x * 32 + (threadIdx.x >> 3);
  int lane = threadIdx.x & 7;
  if (n >= N_NODES) return;
  float acc[8];
#pragma unroll
  for (int i = 0; i < 8; ++i) acc[i] = 0.0f;
  int s = rowptr[n], e = rowptr[n + 1];
  for (int ee = s; ee < e; ++ee) {
    int c = ccol[ee];
    float v = cval[ee];
    uint4 raw = reinterpret_cast<const uint4*>(xcat + (size_t)c * KTOT)[lane];
    const __half2* h = reinterpret_cast<const __half2*>(&raw);
#pragma unroll
    for (int i = 0; i < 4; ++i) {
      float2 x = __half22float2(h[i]);
      acc[2 * i]     += v * x.x;
      acc[2 * i + 1] += v * x.y;
    }
  }
  float4* dst = reinterpret_cast<float4*>(yin + (size_t)n * 64 + lane * 8);
  dst[0] = make_float4(acc[0], acc[1], acc[2], acc[3]);
  dst[1] = make_float4(acc[4], acc[5], acc[6], acc[7]);
}

// Consume one 16B chunk (8 halves) into 4 half2 accumulators via v_pk_fma_f16.
__device__ __forceinline__ void consume8h(const uint4& raw, __half2 v, __half2* acc) {
  const __half2* x = reinterpret_cast<const __half2*>(&raw);
#pragma unroll
  for (int i = 0; i < 4; ++i) acc[i] = __hfma2(v, x[i], acc[i]);
}

// Shared SpMM body: gathers state-part chunks (8..263), one per thread, into accL.
// accL[0..63] filled from yin. Returns with __syncthreads() done.
__device__ __forceinline__ void spmm_body(int n, int t,
                                          const int* __restrict__ rowptr,
                                          const int* __restrict__ ccol,
                                          const float* __restrict__ cval,
                                          const __half* __restrict__ xcat,
                                          const float* __restrict__ yin,
                                          float* accL, int2* eCV) {
  __half2 acc[4];
  acc[0] = acc[1] = acc[2] = acc[3] = __half2half2(__float2half_rn(0.0f));

  const char* xbase = reinterpret_cast<const char*>(xcat) + (size_t)(8 + t) * 16;

  int s = rowptr[n], e = rowptr[n + 1];
  for (int cs = s; cs < e; cs += MAXE) {
    int cnt = min(e - cs, MAXE);
    __syncthreads();
    for (int i = t; i < cnt; i += 256) {
      int c = ccol[cs + i];
      float v = cval[cs + i];
      __half2 hv = __half2half2(__float2half_rn(v));
      int2 cv;
      cv.x = c;
      cv.y = *reinterpret_cast<const int*>(&hv);
      eCV[i] = cv;
    }
    __syncthreads();
    if (cnt > 0) {
      // 3-deep pipeline: up to 2 loads in flight per thread
      int2 cv0 = eCV[0];
      uint4 A = *reinterpret_cast<const uint4*>(xbase + (size_t)cv0.x * 4224);
      __half2 vA = *reinterpret_cast<const __half2*>(&cv0.y);
      uint4 B;
      __half2 vB;
      if (cnt > 1) {
        int2 cv1 = eCV[1];
        B = *reinterpret_cast<const uint4*>(xbase + (size_t)cv1.x * 4224);
        vB = *reinterpret_cast<const __half2*>(&cv1.y);
      }
      for (int j = 0; j + 2 < cnt; ++j) {
        int2 cvn = eCV[j + 2];
        uint4 C = *reinterpret_cast<const uint4*>(xbase + (size_t)cvn.x * 4224);
        __half2 vC = *reinterpret_cast<const __half2*>(&cvn.y);
        consume8h(A, vA, acc);
        A = B; vA = vB; B = C; vB = vC;
      }
      consume8h(A, vA, acc);
      if (cnt > 1) consume8h(B, vB, acc);
    }
  }

  // accL[64 + 8t .. +7] <- acc (fp32)
  float2 p0 = __half22float2(acc[0]);
  float2 p1 = __half22float2(acc[1]);
  float2 p2 = __half22float2(acc[2]);
  float2 p3 = __half22float2(acc[3]);
  float4* a4 = reinterpret_cast<float4*>(accL + 64 + 8 * t);
  a4[0] = make_float4(p0.x, p0.y, p1.x, p1.y);
  a4[1] = make_float4(p2.x, p2.y, p3.x, p3.y);
  if (t < 8) {
    const float4* ys = reinterpret_cast<const float4*>(yin + (size_t)n * 64 + 8 * t);
    float4* yd = reinterpret_cast<float4*>(accL + 8 * t);
    yd[0] = ys[0];
    yd[1] = ys[1];
  }
  __syncthreads();
}

// ---------------- phase 1: SpMM + GEMM(66->128) + sigmoid -> val[n][b][128] fp16 ----------------
__global__ __launch_bounds__(256) void gcn1(const int* __restrict__ rowptr,
                                            const int* __restrict__ ccol,
                                            const float* __restrict__ cval,
                                            const __half* __restrict__ xcat,
                                            const float* __restrict__ yin,
                                            const float* __restrict__ w1,
                                            const float* __restrict__ b1,
                                            __half* __restrict__ val) {
  int n = blockIdx.x, t = threadIdx.x;
  __shared__ float accL[KTOT];     // 8448 B
  __shared__ int2  eCV[MAXE];

  spmm_body(n, t, rowptr, ccol, cval, xcat, yin, accL, eCV);

  // GEMM: out[b][j], b = bg*4.., j = jg*4..
  int bg = t >> 5, jg = t & 31;
  float o[4][4];
#pragma unroll
  for (int i = 0; i < 4; ++i)
#pragma unroll
    for (int j2 = 0; j2 < 4; ++j2) o[i][j2] = 0.0f;

  const float4* av = reinterpret_cast<const float4*>(accL);
  const float4* wv = reinterpret_cast<const float4*>(w1);
  for (int f = 0; f < 66; ++f) {
    float4 a = av[f * 8 + bg];
    float4 w = wv[f * 32 + jg];
    o[0][0] += a.x * w.x; o[0][1] += a.x * w.y; o[0][2] += a.x * w.z; o[0][3] += a.x * w.w;
    o[1][0] += a.y * w.x; o[1][1] += a.y * w.y; o[1][2] += a.y * w.z; o[1][3] += a.y * w.w;
    o[2][0] += a.z * w.x; o[2][1] += a.z * w.y; o[2][2] += a.z * w.z; o[2][3] += a.z * w.w;
    o[3][0] += a.w * w.x; o[3][1] += a.w * w.y; o[3][2] += a.w * w.z; o[3][3] += a.w * w.w;
  }

  float4 bb = *reinterpret_cast<const float4*>(b1 + jg * 4);
  __half* vb = val + (size_t)n * 4096 + jg * 4;
#pragma unroll
  for (int i = 0; i < 4; ++i) {
    int b = bg * 4 + i;
    union { __half2 h[2]; uint2 u; } pk;
    pk.h[0] = __floats2half2_rn(sigmoidf(o[i][0] + bb.x), sigmoidf(o[i][1] + bb.y));
    pk.h[1] = __floats2half2_rn(sigmoidf(o[i][2] + bb.z), sigmoidf(o[i][3] + bb.w));
    *reinterpret_cast<uint2*>(vb + (size_t)b * 128) = pk.u;
  }
}

// ---------------- phase 2: SpMM + GEMM(66->64) + relu + gate -> out ----------------
__global__ __launch_bounds__(256) void gcn2(const int* __restrict__ rowptr,
                                            const int* __restrict__ ccol,
                                            const float* __restrict__ cval,
                                            const __half* __restrict__ xcat,
                                            const float* __restrict__ yin,
                                            const float* __restrict__ w2,
                                            const float* __restrict__ b2,
                                            const __half* __restrict__ val,
                                            const float* __restrict__ state,
                                            float* __restrict__ out) {
  int n = blockIdx.x, t = threadIdx.x;
  __shared__ float accL[KTOT];
  __shared__ int2  eCV[MAXE];

  spmm_body(n, t, rowptr, ccol, cval, xcat, yin, accL, eCV);

  // GEMM: out[b][j], b = bg*2.., j = jg*4..  (bg in [0,16), jg in [0,16))
  int bg = t >> 4, jg = t & 15;
  float o[2][4];
#pragma unroll
  for (int i = 0; i < 2; ++i)
#pragma unroll
    for (int j2 = 0; j2 < 4; ++j2) o[i][j2] = 0.0f;

  const float2* av = reinterpret_cast<const float2*>(accL);
  const float4* wv = reinterpret_cast<const float4*>(w2);
  for (int f = 0; f < 66; ++f) {
    float2 a = av[f * 16 + bg];
    float4 w = wv[f * 16 + jg];
    o[0][0] += a.x * w.x; o[0][1] += a.x * w.y; o[0][2] += a.x * w.z; o[0][3] += a.x * w.w;
    o[1][0] += a.y * w.x; o[1][1] += a.y * w.y; o[1][2] += a.y * w.z; o[1][3] += a.y * w.w;
  }

  float4 bb = *reinterpret_cast<const float4*>(b2 + jg * 4);
  int n2 = n >> 1, no = n & 1;
  const __half* up = val + ((size_t)(5000 + n2)) * 4096 + (size_t)no * 64 + jg * 4;
#pragma unroll
  for (int i = 0; i < 2; ++i) {
    int b = bg * 2 + i;
    size_t idx = (size_t)b * 640000 + (size_t)n * 64 + jg * 4;
    float4 sv = *reinterpret_cast<const float4*>(state + idx);
    union { uint2 u; __half2 h[2]; } pk;
    pk.u = *reinterpret_cast<const uint2*>(up + (size_t)b * 128);
    float2 u01 = __half22float2(pk.h[0]);
    float2 u23 = __half22float2(pk.h[1]);
    float4 h;
    float c0 = fmaxf(o[i][0] + bb.x, 0.0f);
    float c1 = fmaxf(o[i][1] + bb.y, 0.0f);
    float c2 = fmaxf(o[i][2] + bb.z, 0.0f);
    float c3 = fmaxf(o[i][3] + bb.w, 0.0f);
    h.x = u01.x * sv.x + (1.0f - u01.x) * c0;
    h.y = u01.y * sv.y + (1.0f - u01.y) * c1;
    h.z = u23.x * sv.z + (1.0f - u23.x) * c2;
    h.w = u23.y * sv.w + (1.0f - u23.y) * c3;
    *reinterpret_cast<float4*>(out + idx) = h;
  }
}

// ---------------- host ----------------
static inline size_t alignup(size_t x) { return (x + 255) & ~(size_t)255; }

extern "C" void kernel_launch(void* const* d_in, const int* in_sizes, int n_in,
                              void* d_out, int out_size, void* d_ws, size_t ws_size,
                              hipStream_t stream) {
  const float* inputs = (const float*)d_in[0];
  const float* state  = (const float*)d_in[1];
  const int*   m_rows = (const int*)d_in[2];
  const int*   m_cols = (const int*)d_in[3];
  const float* m_vals = (const float*)d_in[4];
  const float* w1     = (const float*)d_in[5];
  const float* b1     = (const float*)d_in[6];
  const float* w2     = (const float*)d_in[7];
  const float* b2     = (const float*)d_in[8];
  float* out = (float*)d_out;

  const int N  = N_NODES;
  const int E2 = in_sizes[2];

  char* ws = (char*)d_ws;
  size_t off = 0;
  int* counts = (int*)(ws + off); off = alignup(off + (size_t)N * 4);
  int* rowptr = (int*)(ws + off); off = alignup(off + (size_t)(N + 1) * 4);
  int* wofs   = (int*)(ws + off); off = alignup(off + (size_t)N * 4);
  int* ccol   = (int*)(ws + off); off = alignup(off + (size_t)E2 * 4);
  float* cval = (float*)(ws + off); off = alignup(off + (size_t)E2 * 4);
  __half* xcat = (__half*)(ws + off); off = alignup(off + (size_t)N * KTOT * 2);
  __half* val  = (__half*)(ws + off); off = alignup(off + (size_t)N * 4096 * 2);
  float* yin  = (float*)(ws + off); off = alignup(off + (size_t)N * 64 * 4);
  if (off > ws_size) { return; }

  hipMemsetAsync(counts, 0, (size_t)N * 4, stream);

  int eb = (E2 + 255) / 256;
  hipLaunchKernelGGL(hist_k,    dim3(eb), dim3(256), 0, stream, m_rows, counts, E2);
  hipLaunchKernelGGL(scan_k,    dim3(1),  dim3(1024), 0, stream, counts, rowptr, wofs, N);
  hipLaunchKernelGGL(scatter_k, dim3(eb), dim3(256), 0, stream, m_rows, m_cols, m_vals,
                     wofs, ccol, cval, E2);
  hipLaunchKernelGGL(build_x1,  dim3(N),  dim3(256), 0, stream, inputs, state, xcat);
  hipLaunchKernelGGL(yin_k,     dim3((N + 31) / 32), dim3(256), 0, stream,
                     rowptr, ccol, cval, xcat, yin);
  hipLaunchKernelGGL(gcn1,      dim3(N),  dim3(256), 0, stream, rowptr, ccol, cval,
                     xcat, yin, w1, b1, val);
  hipLaunchKernelGGL(build_x2,  dim3(N),  dim3(256), 0, stream, inputs, state, val, xcat);
  hipLaunchKernelGGL(gcn2,      dim3(N),  dim3(256), 0, stream, rowptr, ccol, cval,
                     xcat, yin, w2, b2, val, state, out);
}

// Round 5
// 538.042 us; speedup vs baseline: 2.0642x; 1.2233x over previous
//
#include <hip/hip_runtime.h>
#include <hip/hip_fp16.h>
#include <cstdint>
#include <cstdio>

#define N_NODES 10000
#define BATCH   32
#define UNITS   64
#define F_DIM   66            // 2 + 64
#define KTOT    (F_DIM*BATCH) // 2112 fp32 accum elements per node row
#define XROW    2048          // fp8 state-part row bytes (64 f * 32 b)
#define MAXE    128

typedef float v2f __attribute__((ext_vector_type(2)));

__device__ __forceinline__ float sigmoidf(float x) {
  return 1.0f / (1.0f + __expf(-x));
}

// ---------------- CSR build ----------------
__global__ __launch_bounds__(256) void hist_k(const int* __restrict__ rows,
                                              int* __restrict__ counts, int E2) {
  int e = blockIdx.x * 256 + threadIdx.x;
  if (e < E2) atomicAdd(&counts[rows[e]], 1);
}

// 256 threads, 40 elements/thread, one block. ~17 barriers total.
__global__ __launch_bounds__(256) void scan_k(const int* __restrict__ counts,
                                              int* __restrict__ rowptr,
                                              int* __restrict__ wofs, int n) {
  __shared__ int sums[256];
  int t = threadIdx.x;
  int base = t * 40;
  int v[40];
  int run = 0;
#pragma unroll
  for (int i = 0; i < 40; ++i) {
    int idx = base + i;
    int c = (idx < n) ? counts[idx] : 0;
    v[i] = run;               // exclusive prefix within thread
    run += c;
  }
  sums[t] = run;
  __syncthreads();
  for (int off = 1; off < 256; off <<= 1) {
    int x = (t >= off) ? sums[t - off] : 0;
    __syncthreads();
    sums[t] += x;
    __syncthreads();
  }
  int tbase = (t == 0) ? 0 : sums[t - 1];
#pragma unroll
  for (int i = 0; i < 40; ++i) {
    int idx = base + i;
    if (idx < n) { int p = tbase + v[i]; rowptr[idx] = p; wofs[idx] = p; }
  }
  if (t == 255) rowptr[n] = sums[255];
}

__global__ __launch_bounds__(256) void scatter_k(const int* __restrict__ rows,
                                                 const int* __restrict__ cols,
                                                 const float* __restrict__ vals,
                                                 int* __restrict__ wofs,
                                                 int* __restrict__ ccol,
                                                 float* __restrict__ cval, int E2) {
  int e = blockIdx.x * 256 + threadIdx.x;
  if (e < E2) {
    int r = rows[e];
    int p = atomicAdd(&wofs[r], 1);
    ccol[p] = cols[e];
    cval[p] = vals[e];
  }
}

// ---------------- feature builds ----------------
// xcat8[n][k], k = f8*32+b (f8 = f-2, state part) as OCP fp8 e4m3.
// xin[n][k], k = f*32+b for f<2, fp16 (input part, used only by yin_k).
__device__ __forceinline__ void pack_row_fp8(const float* T, int n, int t,
                                             unsigned char* xcat8) {
  int k0 = t * 8;
  int f8 = k0 >> 5;          // 0..63
  int b0 = k0 & 31;          // 0,8,16,24
  const float* Ts = &T[(f8 + 2) * 33 + b0];
  int d0 = __builtin_amdgcn_cvt_pk_fp8_f32(Ts[0], Ts[1], 0, false);
  d0     = __builtin_amdgcn_cvt_pk_fp8_f32(Ts[2], Ts[3], d0, true);
  int d1 = __builtin_amdgcn_cvt_pk_fp8_f32(Ts[4], Ts[5], 0, false);
  d1     = __builtin_amdgcn_cvt_pk_fp8_f32(Ts[6], Ts[7], d1, true);
  *reinterpret_cast<uint2*>(xcat8 + (size_t)n * XROW + k0) = make_uint2(d0, d1);
}

__global__ __launch_bounds__(256) void build_x1(const float* __restrict__ inputs,
                                                const float* __restrict__ state,
                                                unsigned char* __restrict__ xcat8,
                                                __half2* __restrict__ xin) {
  int n = blockIdx.x, t = threadIdx.x;
  __shared__ float T[66 * 33];               // padded transpose tile
  int f = t & 63, bq = t >> 6;               // bq in [0,4)
#pragma unroll
  for (int bb = 0; bb < 8; ++bb) {
    int b = bq + bb * 4;
    T[(f + 2) * 33 + b] = state[(size_t)b * 640000 + (size_t)n * 64 + f];
  }
  if (t < 64) {
    int b0 = t & 31, f0 = t >> 5;
    T[f0 * 33 + b0] = inputs[(size_t)b0 * 20000 + (size_t)n * 2 + f0];
  }
  __syncthreads();
  pack_row_fp8(T, n, t, xcat8);
  if (t < 32) {
    int f0 = t >> 4, b = (t & 15) * 2;       // k = f0*32 + b
    xin[(size_t)n * 32 + t] = __floats2half2_rn(T[f0 * 33 + b], T[f0 * 33 + b + 1]);
  }
}

__global__ __launch_bounds__(256) void build_x2(const float* __restrict__ inputs,
                                                const float* __restrict__ state,
                                                const __half* __restrict__ val,
                                                unsigned char* __restrict__ xcat8) {
  int n = blockIdx.x, t = threadIdx.x;
  __shared__ float T[66 * 33];
  int f = t & 63, bq = t >> 6;
  const __half* vrow = val + ((size_t)(n >> 1)) * 4096 + (size_t)(n & 1) * 64;
#pragma unroll
  for (int bb = 0; bb < 8; ++bb) {
    int b = bq + bb * 4;
    float s = state[(size_t)b * 640000 + (size_t)n * 64 + f];
    float r = __half2float(vrow[(size_t)b * 128 + f]);
    T[(f + 2) * 33 + b] = r * s;
  }
  if (t < 64) {
    int b0 = t & 31, f0 = t >> 5;
    T[f0 * 33 + b0] = inputs[(size_t)b0 * 20000 + (size_t)n * 2 + f0];
  }
  __syncthreads();
  pack_row_fp8(T, n, t, xcat8);
}

// ---------------- yin = M @ X_in (input-feature part, shared by both passes) ----------------
// Gathers from tiny L2-resident xin (1.3 MB). 8 lanes/node, 32 nodes/block.
__global__ __launch_bounds__(256) void yin_k(const int* __restrict__ rowptr,
                                             const int* __restrict__ ccol,
                                             const float* __restrict__ cval,
                                             const __half* __restrict__ xin,
                                             float* __restrict__ yin) {
  int n = blockIdx.x * 32 + (threadIdx.x >> 3);
  int lane = threadIdx.x & 7;
  if (n >= N_NODES) return;
  float acc[8];
#pragma unroll
  for (int i = 0; i < 8; ++i) acc[i] = 0.0f;
  int s = rowptr[n], e = rowptr[n + 1];
  for (int ee = s; ee < e; ++ee) {
    int c = ccol[ee];
    float v = cval[ee];
    uint4 raw = reinterpret_cast<const uint4*>(xin + (size_t)c * 64)[lane];
    const __half2* h = reinterpret_cast<const __half2*>(&raw);
#pragma unroll
    for (int i = 0; i < 4; ++i) {
      float2 x = __half22float2(h[i]);
      acc[2 * i]     += v * x.x;
      acc[2 * i + 1] += v * x.y;
    }
  }
  float4* dst = reinterpret_cast<float4*>(yin + (size_t)n * 64 + lane * 8);
  dst[0] = make_float4(acc[0], acc[1], acc[2], acc[3]);
  dst[1] = make_float4(acc[4], acc[5], acc[6], acc[7]);
}

// Consume one 8B chunk (8 fp8) into 8 fp32 accumulators.
__device__ __forceinline__ void consume8f8(uint2 u, float v, float* acc) {
  v2f p0 = __builtin_amdgcn_cvt_pk_f32_fp8((int)u.x, false);
  v2f p1 = __builtin_amdgcn_cvt_pk_f32_fp8((int)u.x, true);
  v2f p2 = __builtin_amdgcn_cvt_pk_f32_fp8((int)u.y, false);
  v2f p3 = __builtin_amdgcn_cvt_pk_f32_fp8((int)u.y, true);
  acc[0] += v * p0.x; acc[1] += v * p0.y;
  acc[2] += v * p1.x; acc[3] += v * p1.y;
  acc[4] += v * p2.x; acc[5] += v * p2.y;
  acc[6] += v * p3.x; acc[7] += v * p3.y;
}

// Shared SpMM body: each thread gathers one 8B fp8 chunk per edge (state part),
// 4-deep pipeline (3 loads in flight). accL[0..63] from yin, [64..2111] state.
__device__ __forceinline__ void spmm_body(int n, int t,
                                          const int* __restrict__ rowptr,
                                          const int* __restrict__ ccol,
                                          const float* __restrict__ cval,
                                          const unsigned char* __restrict__ xcat8,
                                          const float* __restrict__ yin,
                                          float* accL, int2* eCV) {
  float acc[8];
#pragma unroll
  for (int i = 0; i < 8; ++i) acc[i] = 0.0f;

  const char* xbase = reinterpret_cast<const char*>(xcat8) + (size_t)t * 8;

  int s = rowptr[n], e = rowptr[n + 1];
  for (int cs = s; cs < e; cs += MAXE) {
    int cnt = min(e - cs, MAXE);
    __syncthreads();
    for (int i = t; i < cnt; i += 256) {
      eCV[i] = make_int2(ccol[cs + i], __float_as_int(cval[cs + i]));
    }
    __syncthreads();
    if (cnt > 0) {
      uint2 A, B, C;
      float vA = 0.0f, vB = 0.0f, vC = 0.0f;
      {
        int2 cv = eCV[0];
        A = *reinterpret_cast<const uint2*>(xbase + ((size_t)cv.x << 11));
        vA = __int_as_float(cv.y);
      }
      if (cnt > 1) {
        int2 cv = eCV[1];
        B = *reinterpret_cast<const uint2*>(xbase + ((size_t)cv.x << 11));
        vB = __int_as_float(cv.y);
      }
      if (cnt > 2) {
        int2 cv = eCV[2];
        C = *reinterpret_cast<const uint2*>(xbase + ((size_t)cv.x << 11));
        vC = __int_as_float(cv.y);
      }
      int j = 0;
      for (; j + 3 < cnt; ++j) {
        int2 cv = eCV[j + 3];
        uint2 D = *reinterpret_cast<const uint2*>(xbase + ((size_t)cv.x << 11));
        float vD = __int_as_float(cv.y);
        consume8f8(A, vA, acc);
        A = B; vA = vB; B = C; vB = vC; C = D; vC = vD;
      }
      consume8f8(A, vA, acc);
      if (cnt > 1) consume8f8(B, vB, acc);
      if (cnt > 2) consume8f8(C, vC, acc);
    }
  }

  float4* a4 = reinterpret_cast<float4*>(accL + 64 + 8 * t);
  a4[0] = make_float4(acc[0], acc[1], acc[2], acc[3]);
  a4[1] = make_float4(acc[4], acc[5], acc[6], acc[7]);
  if (t < 8) {
    const float4* ys = reinterpret_cast<const float4*>(yin + (size_t)n * 64 + 8 * t);
    float4* yd = reinterpret_cast<float4*>(accL + 8 * t);
    yd[0] = ys[0];
    yd[1] = ys[1];
  }
  __syncthreads();
}

// ---------------- phase 1: SpMM + GEMM(66->128) + sigmoid -> val[n][b][128] fp16 ----------------
__global__ __launch_bounds__(256) void gcn1(const int* __restrict__ rowptr,
                                            const int* __restrict__ ccol,
                                            const float* __restrict__ cval,
                                            const unsigned char* __restrict__ xcat8,
                                            const float* __restrict__ yin,
                                            const float* __restrict__ w1,
                                            const float* __restrict__ b1,
                                            __half* __restrict__ val) {
  int n = blockIdx.x, t = threadIdx.x;
  __shared__ float accL[KTOT];     // 8448 B
  __shared__ int2  eCV[MAXE];

  spmm_body(n, t, rowptr, ccol, cval, xcat8, yin, accL, eCV);

  // GEMM: out[b][j], b = bg*4.., j = jg*4..
  int bg = t >> 5, jg = t & 31;
  float o[4][4];
#pragma unroll
  for (int i = 0; i < 4; ++i)
#pragma unroll
    for (int j2 = 0; j2 < 4; ++j2) o[i][j2] = 0.0f;

  const float4* av = reinterpret_cast<const float4*>(accL);
  const float4* wv = reinterpret_cast<const float4*>(w1);
  for (int f = 0; f < 66; ++f) {
    float4 a = av[f * 8 + bg];
    float4 w = wv[f * 32 + jg];
    o[0][0] += a.x * w.x; o[0][1] += a.x * w.y; o[0][2] += a.x * w.z; o[0][3] += a.x * w.w;
    o[1][0] += a.y * w.x; o[1][1] += a.y * w.y; o[1][2] += a.y * w.z; o[1][3] += a.y * w.w;
    o[2][0] += a.z * w.x; o[2][1] += a.z * w.y; o[2][2] += a.z * w.z; o[2][3] += a.z * w.w;
    o[3][0] += a.w * w.x; o[3][1] += a.w * w.y; o[3][2] += a.w * w.z; o[3][3] += a.w * w.w;
  }

  float4 bb = *reinterpret_cast<const float4*>(b1 + jg * 4);
  __half* vb = val + (size_t)n * 4096 + jg * 4;
#pragma unroll
  for (int i = 0; i < 4; ++i) {
    int b = bg * 4 + i;
    union { __half2 h[2]; uint2 u; } pk;
    pk.h[0] = __floats2half2_rn(sigmoidf(o[i][0] + bb.x), sigmoidf(o[i][1] + bb.y));
    pk.h[1] = __floats2half2_rn(sigmoidf(o[i][2] + bb.z), sigmoidf(o[i][3] + bb.w));
    *reinterpret_cast<uint2*>(vb + (size_t)b * 128) = pk.u;
  }
}

// ---------------- phase 2: SpMM + GEMM(66->64) + relu + gate -> out ----------------
__global__ __launch_bounds__(256) void gcn2(const int* __restrict__ rowptr,
                                            const int* __restrict__ ccol,
                                            const float* __restrict__ cval,
                                            const unsigned char* __restrict__ xcat8,
                                            const float* __restrict__ yin,
                                            const float* __restrict__ w2,
                                            const float* __restrict__ b2,
                                            const __half* __restrict__ val,
                                            const float* __restrict__ state,
                                            float* __restrict__ out) {
  int n = blockIdx.x, t = threadIdx.x;
  __shared__ float accL[KTOT];
  __shared__ int2  eCV[MAXE];

  spmm_body(n, t, rowptr, ccol, cval, xcat8, yin, accL, eCV);

  // GEMM: out[b][j], b = bg*2.., j = jg*4..  (bg in [0,16), jg in [0,16))
  int bg = t >> 4, jg = t & 15;
  float o[2][4];
#pragma unroll
  for (int i = 0; i < 2; ++i)
#pragma unroll
    for (int j2 = 0; j2 < 4; ++j2) o[i][j2] = 0.0f;

  const float2* av = reinterpret_cast<const float2*>(accL);
  const float4* wv = reinterpret_cast<const float4*>(w2);
  for (int f = 0; f < 66; ++f) {
    float2 a = av[f * 16 + bg];
    float4 w = wv[f * 16 + jg];
    o[0][0] += a.x * w.x; o[0][1] += a.x * w.y; o[0][2] += a.x * w.z; o[0][3] += a.x * w.w;
    o[1][0] += a.y * w.x; o[1][1] += a.y * w.y; o[1][2] += a.y * w.z; o[1][3] += a.y * w.w;
  }

  float4 bb = *reinterpret_cast<const float4*>(b2 + jg * 4);
  int n2 = n >> 1, no = n & 1;
  const __half* up = val + ((size_t)(5000 + n2)) * 4096 + (size_t)no * 64 + jg * 4;
#pragma unroll
  for (int i = 0; i < 2; ++i) {
    int b = bg * 2 + i;
    size_t idx = (size_t)b * 640000 + (size_t)n * 64 + jg * 4;
    float4 sv = *reinterpret_cast<const float4*>(state + idx);
    union { uint2 u; __half2 h[2]; } pk;
    pk.u = *reinterpret_cast<const uint2*>(up + (size_t)b * 128);
    float2 u01 = __half22float2(pk.h[0]);
    float2 u23 = __half22float2(pk.h[1]);
    float4 h;
    float c0 = fmaxf(o[i][0] + bb.x, 0.0f);
    float c1 = fmaxf(o[i][1] + bb.y, 0.0f);
    float c2 = fmaxf(o[i][2] + bb.z, 0.0f);
    float c3 = fmaxf(o[i][3] + bb.w, 0.0f);
    h.x = u01.x * sv.x + (1.0f - u01.x) * c0;
    h.y = u01.y * sv.y + (1.0f - u01.y) * c1;
    h.z = u23.x * sv.z + (1.0f - u23.x) * c2;
    h.w = u23.y * sv.w + (1.0f - u23.y) * c3;
    *reinterpret_cast<float4*>(out + idx) = h;
  }
}

// ---------------- host ----------------
static inline size_t alignup(size_t x) { return (x + 255) & ~(size_t)255; }

extern "C" void kernel_launch(void* const* d_in, const int* in_sizes, int n_in,
                              void* d_out, int out_size, void* d_ws, size_t ws_size,
                              hipStream_t stream) {
  const float* inputs = (const float*)d_in[0];
  const float* state  = (const float*)d_in[1];
  const int*   m_rows = (const int*)d_in[2];
  const int*   m_cols = (const int*)d_in[3];
  const float* m_vals = (const float*)d_in[4];
  const float* w1     = (const float*)d_in[5];
  const float* b1     = (const float*)d_in[6];
  const float* w2     = (const float*)d_in[7];
  const float* b2     = (const float*)d_in[8];
  float* out = (float*)d_out;

  const int N  = N_NODES;
  const int E2 = in_sizes[2];

  char* ws = (char*)d_ws;
  size_t off = 0;
  int* counts = (int*)(ws + off); off = alignup(off + (size_t)N * 4);
  int* rowptr = (int*)(ws + off); off = alignup(off + (size_t)(N + 1) * 4);
  int* wofs   = (int*)(ws + off); off = alignup(off + (size_t)N * 4);
  int* ccol   = (int*)(ws + off); off = alignup(off + (size_t)E2 * 4);
  float* cval = (float*)(ws + off); off = alignup(off + (size_t)E2 * 4);
  unsigned char* xcat8 = (unsigned char*)(ws + off); off = alignup(off + (size_t)N * XROW);
  __half* val = (__half*)(ws + off); off = alignup(off + (size_t)N * 4096 * 2);
  float* yin  = (float*)(ws + off); off = alignup(off + (size_t)N * 64 * 4);
  __half* xin = (__half*)(ws + off); off = alignup(off + (size_t)N * 64 * 2);
  if (off > ws_size) { return; }

  hipMemsetAsync(counts, 0, (size_t)N * 4, stream);

  int eb = (E2 + 255) / 256;
  hipLaunchKernelGGL(hist_k,    dim3(eb), dim3(256), 0, stream, m_rows, counts, E2);
  hipLaunchKernelGGL(scan_k,    dim3(1),  dim3(256), 0, stream, counts, rowptr, wofs, N);
  hipLaunchKernelGGL(scatter_k, dim3(eb), dim3(256), 0, stream, m_rows, m_cols, m_vals,
                     wofs, ccol, cval, E2);
  hipLaunchKernelGGL(build_x1,  dim3(N),  dim3(256), 0, stream, inputs, state, xcat8,
                     (__half2*)xin);
  hipLaunchKernelGGL(yin_k,     dim3((N + 31) / 32), dim3(256), 0, stream,
                     rowptr, ccol, cval, xin, yin);
  hipLaunchKernelGGL(gcn1,      dim3(N),  dim3(256), 0, stream, rowptr, ccol, cval,
                     xcat8, yin, w1, b1, val);
  hipLaunchKernelGGL(build_x2,  dim3(N),  dim3(256), 0, stream, inputs, state, val, xcat8);
  hipLaunchKernelGGL(gcn2,      dim3(N),  dim3(256), 0, stream, rowptr, ccol, cval,
                     xcat8, yin, w2, b2, val, state, out);
}